// Round 20
// baseline (136.856 us; speedup 1.0000x reference)
//
#include <hip/hip_runtime.h>
#include <hip/hip_fp16.h>
#include <math.h>

#define N_NODES 100000
#define N_EDGES 6400000
#define F_IN 36
#define HID 8
#define NCLS 2
#define NEG_SLOPE 0.2f

#define COARSE 256                        // nodes per coarse bucket (dst >> 8)
#define NBC 391                           // ceil(N_NODES/256)
#define CAPC 18432                        // max edges per coarse bucket
#define CHUNK 8192                        // edges per scatter chunk
#define NSTG ((N_EDGES + CHUNK - 1) / CHUNK)   // 782
#define SHIFT1 8.0f                       // softmax shift (softmax is shift-invariant)
#define SHIFT2 16.0f

static __device__ __forceinline__ unsigned pack2h(float a, float b) {
    __half2 h = __float22half2_rn(make_float2(a, b));
    return *reinterpret_cast<unsigned*>(&h);
}
static __device__ __forceinline__ float2 unpack2h(unsigned u) {
    __half2 h = *reinterpret_cast<__half2*>(&u);
    return __half22float2(h);
}

// ------- K0: per-node rec1 (fp16 h) + s1d ----------------------------------
__global__ __launch_bounds__(256) void k0_node(
    const float* __restrict__ x, const float* __restrict__ W1,
    const float* __restrict__ a1d_g,
    uint4* __restrict__ rec1, float* __restrict__ s1d)
{
    __shared__ float sW[F_IN * HID];
    __shared__ float sad[HID];
    int tid = threadIdx.x;
    for (int i = tid; i < F_IN * HID; i += 256) sW[i] = W1[i];
    if (tid < HID) sad[tid] = a1d_g[tid];
    __syncthreads();

    int n = blockIdx.x * 256 + tid;
    if (n >= N_NODES) return;

    const float4* xp = (const float4*)(x + (size_t)n * F_IN);
    float h[HID];
#pragma unroll
    for (int f = 0; f < HID; ++f) h[f] = 0.f;
#pragma unroll
    for (int q = 0; q < F_IN / 4; ++q) {
        float4 v = xp[q];
        float vs[4] = {v.x, v.y, v.z, v.w};
#pragma unroll
        for (int j = 0; j < 4; ++j) {
            int k = q * 4 + j;
#pragma unroll
            for (int f = 0; f < HID; ++f) h[f] = fmaf(vs[j], sW[k * HID + f], h[f]);
        }
    }
    float sd = 0.f;
#pragma unroll
    for (int f = 0; f < HID; ++f) sd = fmaf(h[f], sad[f], sd);

    uint4 w;
    w.x = pack2h(h[0], h[1]);
    w.y = pack2h(h[2], h[3]);
    w.z = pack2h(h[4], h[5]);
    w.w = pack2h(h[6], h[7]);
    rec1[n] = w;
    s1d[n] = sd;
}

// ------- KH: per-chunk bucket histogram -> gcnt[g][b] ----------------------
__global__ __launch_bounds__(256) void kH_hist(const int* __restrict__ dst,
                                               int* __restrict__ gcnt)
{
    __shared__ int lh[NBC];
    int tid = threadIdx.x, g = blockIdx.x;
    for (int i = tid; i < NBC; i += 256) lh[i] = 0;
    __syncthreads();

    int e0 = g * CHUNK;
    int ne = N_EDGES - e0; if (ne > CHUNK) ne = CHUNK;
    int n4 = ne >> 2;
    const int4* dv = (const int4*)(dst + e0);
    for (int i = tid; i < n4; i += 256) {
        int4 d = dv[i];
        atomicAdd(&lh[d.x >> 8], 1);
        atomicAdd(&lh[d.y >> 8], 1);
        atomicAdd(&lh[d.z >> 8], 1);
        atomicAdd(&lh[d.w >> 8], 1);
    }
    __syncthreads();
    for (int i = tid; i < NBC; i += 256) gcnt[(size_t)g * NBC + i] = lh[i];
}

// ------- KS: per-bucket exclusive scan over chunks -> lpre[b][g], tot[b] ---
__global__ __launch_bounds__(256) void kS_scan(const int* __restrict__ gcnt,
                                               int* __restrict__ lpre, int* __restrict__ tot)
{
    __shared__ int sv[256];
    int b = blockIdx.x, tid = threadIdx.x;
    int carry = 0;
    const int ntile = (NSTG + 255) / 256;
    for (int t = 0; t < ntile; ++t) {
        int g = t * 256 + tid;
        int v = (g < NSTG) ? gcnt[(size_t)g * NBC + b] : 0;
        sv[tid] = v;
        __syncthreads();
        for (int off = 1; off < 256; off <<= 1) {
            int x = (tid >= off) ? sv[tid - off] : 0;
            __syncthreads();
            sv[tid] += x;
            __syncthreads();
        }
        if (g < NSTG) lpre[(size_t)b * NSTG + g] = carry + sv[tid] - v;
        carry += sv[255];
        __syncthreads();
    }
    if (tid == 0) tot[b] = carry;
}

// ------- K2b: scan bucket totals -> cbase ----------------------------------
__global__ __launch_bounds__(512) void k2b_cscan(const int* __restrict__ tot,
                                                 int* __restrict__ cbase)
{
    __shared__ int s[512];
    int tid = threadIdx.x;
    int v = (tid < NBC) ? tot[tid] : 0;
    s[tid] = v;
    __syncthreads();
    for (int off = 1; off < 512; off <<= 1) {
        int t = (tid >= off) ? s[tid - off] : 0;
        __syncthreads();
        s[tid] += t;
        __syncthreads();
    }
    int ex = s[tid] - v;
    if (tid < NBC) cbase[tid] = ex;
    if (tid == NBC) cbase[NBC] = ex;   // == N_EDGES
}

// ------- KA: staged scatter — NO global atomics ----------------------------
__global__ __launch_bounds__(1024) void kA_stage(
    const int* __restrict__ src, const int* __restrict__ dst,
    const int* __restrict__ cbase, const int* __restrict__ lpre,
    unsigned int* __restrict__ bdata)
{
    __shared__ unsigned int stg[CHUNK];          // 32 KB
    __shared__ unsigned short aux[CHUNK];        // 16 KB
    __shared__ int lh[NBC];
    __shared__ int lstart[NBC];
    __shared__ int lcur[NBC];
    __shared__ int tbase[NBC];
    int tid = threadIdx.x, g = blockIdx.x;

    for (int i = tid; i < NBC; i += 1024) lh[i] = 0;
    __syncthreads();

    int e0 = g * CHUNK;
    int ne = N_EDGES - e0; if (ne > CHUNK) ne = CHUNK;   // multiple of 4
    int n4 = ne >> 2;
    const int4* dv = (const int4*)(dst + e0);
    const int4* sv = (const int4*)(src + e0);

    int4 d0, s0, d1, s1;
    bool v0 = (tid < n4), v1 = (tid + 1024 < n4);
    if (v0) {
        d0 = dv[tid]; s0 = sv[tid];
        atomicAdd(&lh[d0.x >> 8], 1);
        atomicAdd(&lh[d0.y >> 8], 1);
        atomicAdd(&lh[d0.z >> 8], 1);
        atomicAdd(&lh[d0.w >> 8], 1);
    }
    if (v1) {
        d1 = dv[tid + 1024]; s1 = sv[tid + 1024];
        atomicAdd(&lh[d1.x >> 8], 1);
        atomicAdd(&lh[d1.y >> 8], 1);
        atomicAdd(&lh[d1.z >> 8], 1);
        atomicAdd(&lh[d1.w >> 8], 1);
    }
    __syncthreads();

    if (tid < 64) {
        int base = tid * 7;
        int cnt[7];
        int s = 0;
#pragma unroll
        for (int k = 0; k < 7; ++k) {
            int b = base + k;
            cnt[k] = (b < NBC) ? lh[b] : 0;
            s += cnt[k];
        }
        int inc = s;
#pragma unroll
        for (int off = 1; off < 64; off <<= 1) {
            int t2 = __shfl_up(inc, off);
            if (tid >= off) inc += t2;
        }
        int ex = inc - s;
#pragma unroll
        for (int k = 0; k < 7; ++k) {
            int b = base + k;
            if (b < NBC) { lstart[b] = ex; lcur[b] = ex; ex += cnt[k]; }
        }
    }
    __syncthreads();

    for (int b = tid; b < NBC; b += 1024) {
        tbase[b] = cbase[b] + lpre[(size_t)b * NSTG + g];
    }

    if (v0) {
        int b, p;
        b = d0.x >> 8; p = atomicAdd(&lcur[b], 1); stg[p] = (unsigned)s0.x | ((unsigned)(d0.x & 255) << 17); aux[p] = (unsigned short)b;
        b = d0.y >> 8; p = atomicAdd(&lcur[b], 1); stg[p] = (unsigned)s0.y | ((unsigned)(d0.y & 255) << 17); aux[p] = (unsigned short)b;
        b = d0.z >> 8; p = atomicAdd(&lcur[b], 1); stg[p] = (unsigned)s0.z | ((unsigned)(d0.z & 255) << 17); aux[p] = (unsigned short)b;
        b = d0.w >> 8; p = atomicAdd(&lcur[b], 1); stg[p] = (unsigned)s0.w | ((unsigned)(d0.w & 255) << 17); aux[p] = (unsigned short)b;
    }
    if (v1) {
        int b, p;
        b = d1.x >> 8; p = atomicAdd(&lcur[b], 1); stg[p] = (unsigned)s1.x | ((unsigned)(d1.x & 255) << 17); aux[p] = (unsigned short)b;
        b = d1.y >> 8; p = atomicAdd(&lcur[b], 1); stg[p] = (unsigned)s1.y | ((unsigned)(d1.y & 255) << 17); aux[p] = (unsigned short)b;
        b = d1.z >> 8; p = atomicAdd(&lcur[b], 1); stg[p] = (unsigned)s1.z | ((unsigned)(d1.z & 255) << 17); aux[p] = (unsigned short)b;
        b = d1.w >> 8; p = atomicAdd(&lcur[b], 1); stg[p] = (unsigned)s1.w | ((unsigned)(d1.w & 255) << 17); aux[p] = (unsigned short)b;
    }
    __syncthreads();

    for (int i = tid; i < ne; i += 1024) {
        int bb = aux[i];
        bdata[tbase[bb] + (i - lstart[bb])] = stg[i];
    }
}

// ------- KB: LDS->LDS node sort, coalesced writeback (1024T) ---------------
__global__ __launch_bounds__(1024) void kB_sort(
    const int* __restrict__ cbase, unsigned int* __restrict__ bdata,
    int* __restrict__ nptr)
{
    __shared__ unsigned int raw[CAPC];    // 72 KB
    __shared__ unsigned int srt[CAPC];    // 72 KB
    __shared__ int cnt[COARSE];
    __shared__ int sstart[COARSE];
    __shared__ int cur[COARSE];
    int tid = threadIdx.x;
    int c = blockIdx.x;
    int cb0 = cbase[c], cb1 = cbase[c + 1];
    int ne = cb1 - cb0;

    if (tid < COARSE) cnt[tid] = 0;
    __syncthreads();

    for (int i = tid; i < ne; i += 1024) {
        unsigned pk = bdata[cb0 + i];
        raw[i] = pk;
        atomicAdd(&cnt[pk >> 17], 1);
    }
    __syncthreads();

    if (tid < 64) {
        int base = tid * 4;
        int c0 = cnt[base], c1 = cnt[base + 1], c2 = cnt[base + 2], c3 = cnt[base + 3];
        int s = c0 + c1 + c2 + c3;
        int inc = s;
#pragma unroll
        for (int off = 1; off < 64; off <<= 1) {
            int t2 = __shfl_up(inc, off);
            if (tid >= off) inc += t2;
        }
        int ex = inc - s;
        sstart[base]     = ex; cur[base]     = ex; ex += c0;
        sstart[base + 1] = ex; cur[base + 1] = ex; ex += c1;
        sstart[base + 2] = ex; cur[base + 2] = ex; ex += c2;
        sstart[base + 3] = ex; cur[base + 3] = ex;
    }
    __syncthreads();

    if (tid < COARSE) {
        int nid = c * COARSE + tid;
        if (nid < N_NODES) nptr[nid] = cb0 + sstart[tid];
    }
    if (c == 0 && tid == 0) nptr[N_NODES] = N_EDGES;

    for (int i = tid; i < ne; i += 1024) {
        unsigned pk = raw[i];
        int p = atomicAdd(&cur[pk >> 17], 1);
        srt[p] = pk & 0x1FFFF;
    }
    __syncthreads();

    for (int i = tid; i < ne; i += 1024) bdata[cb0 + i] = srt[i];
}

// ---------------- KAgg1: layer-1 agg, int4 index loads + uint4 gathers -----
__global__ __launch_bounds__(256) void kAgg1(
    const int* __restrict__ nptr, const unsigned int* __restrict__ bdata,
    const uint4* __restrict__ rec1, const float* __restrict__ s1d,
    const float* __restrict__ a1s_g,
    const float* __restrict__ b1, const float* __restrict__ W2,
    float2* __restrict__ rec2)
{
    int gi = blockIdx.x * 256 + threadIdx.x;
    int n = gi >> 4, q = gi & 15;
    if (n >= N_NODES) return;

    float as0 = a1s_g[0], as1 = a1s_g[1], as2 = a1s_g[2], as3 = a1s_g[3];
    float as4 = a1s_g[4], as5 = a1s_g[5], as6 = a1s_g[6], as7 = a1s_g[7];

    int e0 = nptr[n], e1 = nptr[n + 1];
    float sdvn = s1d[n];
    float z = 0.f;
    float acc[HID];
#pragma unroll
    for (int f = 0; f < HID; ++f) acc[f] = 0.f;

    // scalar prologue to 4-aligned start
    int a0i = (e0 + 3) & ~3;
    int mn = (a0i < e1) ? a0i : e1;
    for (int j = e0 + q; j < mn; j += 16) {
        int s = bdata[j];
        uint4 hv = rec1[s];
        float2 f01 = unpack2h(hv.x), f23 = unpack2h(hv.y);
        float2 f45 = unpack2h(hv.z), f67 = unpack2h(hv.w);
        float ss = f01.x*as0 + f01.y*as1 + f23.x*as2 + f23.y*as3
                 + f45.x*as4 + f45.y*as5 + f67.x*as6 + f67.y*as7;
        float e = ss + sdvn;
        e = (e > 0.f) ? e : NEG_SLOPE * e;
        float p = __expf(e - SHIFT1);
        z += p;
        acc[0] += p * f01.x; acc[1] += p * f01.y;
        acc[2] += p * f23.x; acc[3] += p * f23.y;
        acc[4] += p * f45.x; acc[5] += p * f45.y;
        acc[6] += p * f67.x; acc[7] += p * f67.y;
    }

    int nb4 = (e1 > a0i) ? ((e1 - a0i) >> 2) : 0;
    const int4* bq = (const int4*)(bdata + a0i);
    for (int qi = q; qi < nb4; qi += 16) {
        int4 quad = bq[qi];
        uint4 ha = rec1[quad.x];
        uint4 hb = rec1[quad.y];
        uint4 hc = rec1[quad.z];
        uint4 hd = rec1[quad.w];
        float2 fa01 = unpack2h(ha.x), fa23 = unpack2h(ha.y), fa45 = unpack2h(ha.z), fa67 = unpack2h(ha.w);
        float2 fb01 = unpack2h(hb.x), fb23 = unpack2h(hb.y), fb45 = unpack2h(hb.z), fb67 = unpack2h(hb.w);
        float2 fc01 = unpack2h(hc.x), fc23 = unpack2h(hc.y), fc45 = unpack2h(hc.z), fc67 = unpack2h(hc.w);
        float2 fd01 = unpack2h(hd.x), fd23 = unpack2h(hd.y), fd45 = unpack2h(hd.z), fd67 = unpack2h(hd.w);
        float ssA = fa01.x*as0 + fa01.y*as1 + fa23.x*as2 + fa23.y*as3
                  + fa45.x*as4 + fa45.y*as5 + fa67.x*as6 + fa67.y*as7;
        float ssB = fb01.x*as0 + fb01.y*as1 + fb23.x*as2 + fb23.y*as3
                  + fb45.x*as4 + fb45.y*as5 + fb67.x*as6 + fb67.y*as7;
        float ssC = fc01.x*as0 + fc01.y*as1 + fc23.x*as2 + fc23.y*as3
                  + fc45.x*as4 + fc45.y*as5 + fc67.x*as6 + fc67.y*as7;
        float ssD = fd01.x*as0 + fd01.y*as1 + fd23.x*as2 + fd23.y*as3
                  + fd45.x*as4 + fd45.y*as5 + fd67.x*as6 + fd67.y*as7;
        float eA = ssA + sdvn; eA = (eA > 0.f) ? eA : NEG_SLOPE * eA;
        float eB = ssB + sdvn; eB = (eB > 0.f) ? eB : NEG_SLOPE * eB;
        float eC = ssC + sdvn; eC = (eC > 0.f) ? eC : NEG_SLOPE * eC;
        float eD = ssD + sdvn; eD = (eD > 0.f) ? eD : NEG_SLOPE * eD;
        float pA = __expf(eA - SHIFT1);
        float pB = __expf(eB - SHIFT1);
        float pC = __expf(eC - SHIFT1);
        float pD = __expf(eD - SHIFT1);
        z += (pA + pB) + (pC + pD);
        acc[0] += pA * fa01.x + pB * fb01.x + pC * fc01.x + pD * fd01.x;
        acc[1] += pA * fa01.y + pB * fb01.y + pC * fc01.y + pD * fd01.y;
        acc[2] += pA * fa23.x + pB * fb23.x + pC * fc23.x + pD * fd23.x;
        acc[3] += pA * fa23.y + pB * fb23.y + pC * fc23.y + pD * fd23.y;
        acc[4] += pA * fa45.x + pB * fb45.x + pC * fc45.x + pD * fd45.x;
        acc[5] += pA * fa45.y + pB * fb45.y + pC * fc45.y + pD * fd45.y;
        acc[6] += pA * fa67.x + pB * fb67.x + pC * fc67.x + pD * fd67.x;
        acc[7] += pA * fa67.y + pB * fb67.y + pC * fc67.y + pD * fd67.y;
    }

    // scalar tail
    for (int j = a0i + 4 * nb4 + q; j < e1; j += 16) {
        int s = bdata[j];
        uint4 hv = rec1[s];
        float2 f01 = unpack2h(hv.x), f23 = unpack2h(hv.y);
        float2 f45 = unpack2h(hv.z), f67 = unpack2h(hv.w);
        float ss = f01.x*as0 + f01.y*as1 + f23.x*as2 + f23.y*as3
                 + f45.x*as4 + f45.y*as5 + f67.x*as6 + f67.y*as7;
        float e = ss + sdvn;
        e = (e > 0.f) ? e : NEG_SLOPE * e;
        float p = __expf(e - SHIFT1);
        z += p;
        acc[0] += p * f01.x; acc[1] += p * f01.y;
        acc[2] += p * f23.x; acc[3] += p * f23.y;
        acc[4] += p * f45.x; acc[5] += p * f45.y;
        acc[6] += p * f67.x; acc[7] += p * f67.y;
    }

#pragma unroll
    for (int off = 1; off < 16; off <<= 1) {
        z += __shfl_xor(z, off);
#pragma unroll
        for (int f = 0; f < HID; ++f) acc[f] += __shfl_xor(acc[f], off);
    }

    if (q == 0) {
        float inv = 1.f / (z + 1e-16f);
        float c0 = 0.f, c1 = 0.f;
#pragma unroll
        for (int f = 0; f < HID; ++f) {
            float hr = fmaxf(acc[f] * inv + b1[f], 0.f);
            c0 = fmaf(hr, W2[f * NCLS + 0], c0);
            c1 = fmaf(hr, W2[f * NCLS + 1], c1);
        }
        rec2[n] = make_float2(c0, c1);
    }
}

// ---------------- KAgg2: layer-2 agg, int4 index loads + float2 gathers ----
__global__ __launch_bounds__(256) void kAgg2(
    const int* __restrict__ nptr, const unsigned int* __restrict__ bdata,
    const float2* __restrict__ rec2,
    const float* __restrict__ a2s, const float* __restrict__ a2d,
    const float* __restrict__ b2, float* __restrict__ out)
{
    int gi = blockIdx.x * 256 + threadIdx.x;
    int n = gi >> 4, q = gi & 15;
    if (n >= N_NODES) return;

    float ws0 = a2s[0], ws1 = a2s[1];
    float wd0 = a2d[0], wd1 = a2d[1];

    int e0 = nptr[n], e1 = nptr[n + 1];
    float2 rn = rec2[n];
    float sdvn = rn.x * wd0 + rn.y * wd1;
    float z = 0.f, a0 = 0.f, a1 = 0.f;

    int a0i = (e0 + 3) & ~3;
    int mn = (a0i < e1) ? a0i : e1;
    for (int j = e0 + q; j < mn; j += 16) {
        int s = bdata[j];
        float2 r = rec2[s];
        float e = r.x * ws0 + r.y * ws1 + sdvn;
        e = (e > 0.f) ? e : NEG_SLOPE * e;
        float p = __expf(e - SHIFT2);
        z += p; a0 += p * r.x; a1 += p * r.y;
    }

    int nb4 = (e1 > a0i) ? ((e1 - a0i) >> 2) : 0;
    const int4* bq = (const int4*)(bdata + a0i);
    for (int qi = q; qi < nb4; qi += 16) {
        int4 quad = bq[qi];
        float2 rA = rec2[quad.x];
        float2 rB = rec2[quad.y];
        float2 rC = rec2[quad.z];
        float2 rD = rec2[quad.w];
        float eA = rA.x * ws0 + rA.y * ws1 + sdvn; eA = (eA > 0.f) ? eA : NEG_SLOPE * eA;
        float eB = rB.x * ws0 + rB.y * ws1 + sdvn; eB = (eB > 0.f) ? eB : NEG_SLOPE * eB;
        float eC = rC.x * ws0 + rC.y * ws1 + sdvn; eC = (eC > 0.f) ? eC : NEG_SLOPE * eC;
        float eD = rD.x * ws0 + rD.y * ws1 + sdvn; eD = (eD > 0.f) ? eD : NEG_SLOPE * eD;
        float pA = __expf(eA - SHIFT2);
        float pB = __expf(eB - SHIFT2);
        float pC = __expf(eC - SHIFT2);
        float pD = __expf(eD - SHIFT2);
        z += (pA + pB) + (pC + pD);
        a0 += pA * rA.x + pB * rB.x + pC * rC.x + pD * rD.x;
        a1 += pA * rA.y + pB * rB.y + pC * rC.y + pD * rD.y;
    }

    for (int j = a0i + 4 * nb4 + q; j < e1; j += 16) {
        int s = bdata[j];
        float2 r = rec2[s];
        float e = r.x * ws0 + r.y * ws1 + sdvn;
        e = (e > 0.f) ? e : NEG_SLOPE * e;
        float p = __expf(e - SHIFT2);
        z += p; a0 += p * r.x; a1 += p * r.y;
    }

#pragma unroll
    for (int off = 1; off < 16; off <<= 1) {
        z  += __shfl_xor(z, off);
        a0 += __shfl_xor(a0, off);
        a1 += __shfl_xor(a1, off);
    }

    if (q == 0) {
        float inv = 1.f / (z + 1e-16f);
        float o0 = a0 * inv + b2[0];
        float o1 = a1 * inv + b2[1];
        float mx = fmaxf(o0, o1);
        float lse = mx + __logf(__expf(o0 - mx) + __expf(o1 - mx));
        ((float2*)out)[n] = make_float2(o0 - lse, o1 - lse);
    }
}

// ---------------- host launch ----------------------------------------------
extern "C" void kernel_launch(void* const* d_in, const int* in_sizes, int n_in,
                              void* d_out, int out_size, void* d_ws, size_t ws_size,
                              hipStream_t stream) {
    const float* x   = (const float*)d_in[0];
    const float* W1  = (const float*)d_in[1];
    const float* a1s = (const float*)d_in[2];
    const float* a1d = (const float*)d_in[3];
    const float* b1  = (const float*)d_in[4];
    const float* W2  = (const float*)d_in[5];
    const float* a2s = (const float*)d_in[6];
    const float* a2d = (const float*)d_in[7];
    const float* b2  = (const float*)d_in[8];
    const int*   ei  = (const int*)d_in[9];
    const int* src = ei;
    const int* dst = ei + N_EDGES;

    char* ws = (char*)d_ws;
    uint4*  rec1  = (uint4*) (ws + 0);              // 1,600,000 (100000 x 16B)
    float*  s1d   = (float*) (ws + 1600000);        //   400,000
    float2* rec2  = (float2*)(ws + 2000000);        //   800,000
    int*    nptr  = (int*)   (ws + 2800000);        //   400,016
    int*    cbase = (int*)   (ws + 3200064);        //     1,568 -> pad
    int*    tot   = (int*)   (ws + 3201664);        //     1,564 -> pad
    unsigned int* bdata = (unsigned int*)(ws + 3203264);  // 25,600,000 -> ends 28,803,264
    int*    gcnt  = (int*)   (ws + 28803264);       // 782x391x4 = 1,223,048
    int*    lpre  = (int*)   (ws + 30026312);       // 391x782x4 = 1,223,048 -> ends 31,249,360

    float* out = (float*)d_out;

    k0_node<<<(N_NODES + 255) / 256, 256, 0, stream>>>(x, W1, a1d, rec1, s1d);
    kH_hist<<<NSTG, 256, 0, stream>>>(dst, gcnt);
    kS_scan<<<NBC, 256, 0, stream>>>(gcnt, lpre, tot);
    k2b_cscan<<<1, 512, 0, stream>>>(tot, cbase);
    kA_stage<<<NSTG, 1024, 0, stream>>>(src, dst, cbase, lpre, bdata);
    kB_sort<<<NBC, 1024, 0, stream>>>(cbase, bdata, nptr);
    kAgg1<<<(N_NODES * 16 + 255) / 256, 256, 0, stream>>>(nptr, bdata, rec1, s1d, a1s,
                                                          b1, W2, rec2);
    kAgg2<<<(N_NODES * 16 + 255) / 256, 256, 0, stream>>>(nptr, bdata, rec2,
                                                          a2s, a2d, b2, out);
}

// Round 21
// 132.306 us; speedup vs baseline: 1.0344x; 1.0344x over previous
//
#include <hip/hip_runtime.h>
#include <hip/hip_fp16.h>
#include <math.h>

#define N_NODES 100000
#define N_EDGES 6400000
#define F_IN 36
#define HID 8
#define NCLS 2
#define NEG_SLOPE 0.2f

#define COARSE 256                        // nodes per coarse bucket (dst >> 8)
#define NBC 391                           // ceil(N_NODES/256)
#define CAPC 18432                        // max edges per coarse bucket
#define CHUNK 8192                        // edges per scatter chunk
#define NSTG ((N_EDGES + CHUNK - 1) / CHUNK)   // 782
#define SHIFT1 8.0f                       // softmax shift (softmax is shift-invariant)
#define SHIFT2 16.0f

static __device__ __forceinline__ unsigned pack2h(float a, float b) {
    __half2 h = __float22half2_rn(make_float2(a, b));
    return *reinterpret_cast<unsigned*>(&h);
}
static __device__ __forceinline__ float2 unpack2h(unsigned u) {
    __half2 h = *reinterpret_cast<__half2*>(&u);
    return __half22float2(h);
}

// ------- K0: per-node rec1 (fp16 h) + s1d ----------------------------------
__global__ __launch_bounds__(256) void k0_node(
    const float* __restrict__ x, const float* __restrict__ W1,
    const float* __restrict__ a1d_g,
    uint4* __restrict__ rec1, float* __restrict__ s1d)
{
    __shared__ float sW[F_IN * HID];
    __shared__ float sad[HID];
    int tid = threadIdx.x;
    for (int i = tid; i < F_IN * HID; i += 256) sW[i] = W1[i];
    if (tid < HID) sad[tid] = a1d_g[tid];
    __syncthreads();

    int n = blockIdx.x * 256 + tid;
    if (n >= N_NODES) return;

    const float4* xp = (const float4*)(x + (size_t)n * F_IN);
    float h[HID];
#pragma unroll
    for (int f = 0; f < HID; ++f) h[f] = 0.f;
#pragma unroll
    for (int q = 0; q < F_IN / 4; ++q) {
        float4 v = xp[q];
        float vs[4] = {v.x, v.y, v.z, v.w};
#pragma unroll
        for (int j = 0; j < 4; ++j) {
            int k = q * 4 + j;
#pragma unroll
            for (int f = 0; f < HID; ++f) h[f] = fmaf(vs[j], sW[k * HID + f], h[f]);
        }
    }
    float sd = 0.f;
#pragma unroll
    for (int f = 0; f < HID; ++f) sd = fmaf(h[f], sad[f], sd);

    uint4 w;
    w.x = pack2h(h[0], h[1]);
    w.y = pack2h(h[2], h[3]);
    w.z = pack2h(h[4], h[5]);
    w.w = pack2h(h[6], h[7]);
    rec1[n] = w;
    s1d[n] = sd;
}

// ------- KH: per-chunk bucket histogram -> gcnt[g][b] ----------------------
__global__ __launch_bounds__(256) void kH_hist(const int* __restrict__ dst,
                                               int* __restrict__ gcnt)
{
    __shared__ int lh[NBC];
    int tid = threadIdx.x, g = blockIdx.x;
    for (int i = tid; i < NBC; i += 256) lh[i] = 0;
    __syncthreads();

    int e0 = g * CHUNK;
    int ne = N_EDGES - e0; if (ne > CHUNK) ne = CHUNK;
    int n4 = ne >> 2;
    const int4* dv = (const int4*)(dst + e0);
    for (int i = tid; i < n4; i += 256) {
        int4 d = dv[i];
        atomicAdd(&lh[d.x >> 8], 1);
        atomicAdd(&lh[d.y >> 8], 1);
        atomicAdd(&lh[d.z >> 8], 1);
        atomicAdd(&lh[d.w >> 8], 1);
    }
    __syncthreads();
    for (int i = tid; i < NBC; i += 256) gcnt[(size_t)g * NBC + i] = lh[i];
}

// ------- KS: per-bucket exclusive scan over chunks -> lpre[b][g], tot[b] ---
__global__ __launch_bounds__(256) void kS_scan(const int* __restrict__ gcnt,
                                               int* __restrict__ lpre, int* __restrict__ tot)
{
    __shared__ int sv[256];
    int b = blockIdx.x, tid = threadIdx.x;
    int carry = 0;
    const int ntile = (NSTG + 255) / 256;
    for (int t = 0; t < ntile; ++t) {
        int g = t * 256 + tid;
        int v = (g < NSTG) ? gcnt[(size_t)g * NBC + b] : 0;
        sv[tid] = v;
        __syncthreads();
        for (int off = 1; off < 256; off <<= 1) {
            int x = (tid >= off) ? sv[tid - off] : 0;
            __syncthreads();
            sv[tid] += x;
            __syncthreads();
        }
        if (g < NSTG) lpre[(size_t)b * NSTG + g] = carry + sv[tid] - v;
        carry += sv[255];
        __syncthreads();
    }
    if (tid == 0) tot[b] = carry;
}

// ------- K2b: scan bucket totals -> cbase ----------------------------------
__global__ __launch_bounds__(512) void k2b_cscan(const int* __restrict__ tot,
                                                 int* __restrict__ cbase)
{
    __shared__ int s[512];
    int tid = threadIdx.x;
    int v = (tid < NBC) ? tot[tid] : 0;
    s[tid] = v;
    __syncthreads();
    for (int off = 1; off < 512; off <<= 1) {
        int t = (tid >= off) ? s[tid - off] : 0;
        __syncthreads();
        s[tid] += t;
        __syncthreads();
    }
    int ex = s[tid] - v;
    if (tid < NBC) cbase[tid] = ex;
    if (tid == NBC) cbase[NBC] = ex;   // == N_EDGES
}

// ------- KA: staged scatter — NO global atomics ----------------------------
__global__ __launch_bounds__(1024) void kA_stage(
    const int* __restrict__ src, const int* __restrict__ dst,
    const int* __restrict__ cbase, const int* __restrict__ lpre,
    unsigned int* __restrict__ bdata)
{
    __shared__ unsigned int stg[CHUNK];          // 32 KB
    __shared__ unsigned short aux[CHUNK];        // 16 KB
    __shared__ int lh[NBC];
    __shared__ int lstart[NBC];
    __shared__ int lcur[NBC];
    __shared__ int tbase[NBC];
    int tid = threadIdx.x, g = blockIdx.x;

    for (int i = tid; i < NBC; i += 1024) lh[i] = 0;
    __syncthreads();

    int e0 = g * CHUNK;
    int ne = N_EDGES - e0; if (ne > CHUNK) ne = CHUNK;   // multiple of 4
    int n4 = ne >> 2;
    const int4* dv = (const int4*)(dst + e0);
    const int4* sv = (const int4*)(src + e0);

    int4 d0, s0, d1, s1;
    bool v0 = (tid < n4), v1 = (tid + 1024 < n4);
    if (v0) {
        d0 = dv[tid]; s0 = sv[tid];
        atomicAdd(&lh[d0.x >> 8], 1);
        atomicAdd(&lh[d0.y >> 8], 1);
        atomicAdd(&lh[d0.z >> 8], 1);
        atomicAdd(&lh[d0.w >> 8], 1);
    }
    if (v1) {
        d1 = dv[tid + 1024]; s1 = sv[tid + 1024];
        atomicAdd(&lh[d1.x >> 8], 1);
        atomicAdd(&lh[d1.y >> 8], 1);
        atomicAdd(&lh[d1.z >> 8], 1);
        atomicAdd(&lh[d1.w >> 8], 1);
    }
    __syncthreads();

    if (tid < 64) {
        int base = tid * 7;
        int cnt[7];
        int s = 0;
#pragma unroll
        for (int k = 0; k < 7; ++k) {
            int b = base + k;
            cnt[k] = (b < NBC) ? lh[b] : 0;
            s += cnt[k];
        }
        int inc = s;
#pragma unroll
        for (int off = 1; off < 64; off <<= 1) {
            int t2 = __shfl_up(inc, off);
            if (tid >= off) inc += t2;
        }
        int ex = inc - s;
#pragma unroll
        for (int k = 0; k < 7; ++k) {
            int b = base + k;
            if (b < NBC) { lstart[b] = ex; lcur[b] = ex; ex += cnt[k]; }
        }
    }
    __syncthreads();

    for (int b = tid; b < NBC; b += 1024) {
        tbase[b] = cbase[b] + lpre[(size_t)b * NSTG + g];
    }

    if (v0) {
        int b, p;
        b = d0.x >> 8; p = atomicAdd(&lcur[b], 1); stg[p] = (unsigned)s0.x | ((unsigned)(d0.x & 255) << 17); aux[p] = (unsigned short)b;
        b = d0.y >> 8; p = atomicAdd(&lcur[b], 1); stg[p] = (unsigned)s0.y | ((unsigned)(d0.y & 255) << 17); aux[p] = (unsigned short)b;
        b = d0.z >> 8; p = atomicAdd(&lcur[b], 1); stg[p] = (unsigned)s0.z | ((unsigned)(d0.z & 255) << 17); aux[p] = (unsigned short)b;
        b = d0.w >> 8; p = atomicAdd(&lcur[b], 1); stg[p] = (unsigned)s0.w | ((unsigned)(d0.w & 255) << 17); aux[p] = (unsigned short)b;
    }
    if (v1) {
        int b, p;
        b = d1.x >> 8; p = atomicAdd(&lcur[b], 1); stg[p] = (unsigned)s1.x | ((unsigned)(d1.x & 255) << 17); aux[p] = (unsigned short)b;
        b = d1.y >> 8; p = atomicAdd(&lcur[b], 1); stg[p] = (unsigned)s1.y | ((unsigned)(d1.y & 255) << 17); aux[p] = (unsigned short)b;
        b = d1.z >> 8; p = atomicAdd(&lcur[b], 1); stg[p] = (unsigned)s1.z | ((unsigned)(d1.z & 255) << 17); aux[p] = (unsigned short)b;
        b = d1.w >> 8; p = atomicAdd(&lcur[b], 1); stg[p] = (unsigned)s1.w | ((unsigned)(d1.w & 255) << 17); aux[p] = (unsigned short)b;
    }
    __syncthreads();

    for (int i = tid; i < ne; i += 1024) {
        int bb = aux[i];
        bdata[tbase[bb] + (i - lstart[bb])] = stg[i];
    }
}

// ------- KB: LDS->LDS node sort, coalesced writeback (1024T) ---------------
__global__ __launch_bounds__(1024) void kB_sort(
    const int* __restrict__ cbase, unsigned int* __restrict__ bdata,
    int* __restrict__ nptr)
{
    __shared__ unsigned int raw[CAPC];    // 72 KB
    __shared__ unsigned int srt[CAPC];    // 72 KB
    __shared__ int cnt[COARSE];
    __shared__ int sstart[COARSE];
    __shared__ int cur[COARSE];
    int tid = threadIdx.x;
    int c = blockIdx.x;
    int cb0 = cbase[c], cb1 = cbase[c + 1];
    int ne = cb1 - cb0;

    if (tid < COARSE) cnt[tid] = 0;
    __syncthreads();

    for (int i = tid; i < ne; i += 1024) {
        unsigned pk = bdata[cb0 + i];
        raw[i] = pk;
        atomicAdd(&cnt[pk >> 17], 1);
    }
    __syncthreads();

    if (tid < 64) {
        int base = tid * 4;
        int c0 = cnt[base], c1 = cnt[base + 1], c2 = cnt[base + 2], c3 = cnt[base + 3];
        int s = c0 + c1 + c2 + c3;
        int inc = s;
#pragma unroll
        for (int off = 1; off < 64; off <<= 1) {
            int t2 = __shfl_up(inc, off);
            if (tid >= off) inc += t2;
        }
        int ex = inc - s;
        sstart[base]     = ex; cur[base]     = ex; ex += c0;
        sstart[base + 1] = ex; cur[base + 1] = ex; ex += c1;
        sstart[base + 2] = ex; cur[base + 2] = ex; ex += c2;
        sstart[base + 3] = ex; cur[base + 3] = ex;
    }
    __syncthreads();

    if (tid < COARSE) {
        int nid = c * COARSE + tid;
        if (nid < N_NODES) nptr[nid] = cb0 + sstart[tid];
    }
    if (c == 0 && tid == 0) nptr[N_NODES] = N_EDGES;

    for (int i = tid; i < ne; i += 1024) {
        unsigned pk = raw[i];
        int p = atomicAdd(&cur[pk >> 17], 1);
        srt[p] = pk & 0x1FFFF;
    }
    __syncthreads();

    for (int i = tid; i < ne; i += 1024) bdata[cb0 + i] = srt[i];
}

// ---------------- KAgg1: layer-1 agg, ONE uint4 gather per edge ------------
__global__ __launch_bounds__(256) void kAgg1(
    const int* __restrict__ nptr, const unsigned int* __restrict__ bdata,
    const uint4* __restrict__ rec1, const float* __restrict__ s1d,
    const float* __restrict__ a1s_g,
    const float* __restrict__ b1, const float* __restrict__ W2,
    float2* __restrict__ rec2)
{
    int gi = blockIdx.x * 256 + threadIdx.x;
    int n = gi >> 4, q = gi & 15;
    if (n >= N_NODES) return;

    float as0 = a1s_g[0], as1 = a1s_g[1], as2 = a1s_g[2], as3 = a1s_g[3];
    float as4 = a1s_g[4], as5 = a1s_g[5], as6 = a1s_g[6], as7 = a1s_g[7];

    int e0 = nptr[n], e1 = nptr[n + 1];
    float sdvn = s1d[n];
    float z = 0.f;
    float acc[HID];
#pragma unroll
    for (int f = 0; f < HID; ++f) acc[f] = 0.f;

    int j = e0 + q;
    for (; j + 48 < e1; j += 64) {
        int sA = bdata[j], sB = bdata[j + 16], sC = bdata[j + 32], sD = bdata[j + 48];
        uint4 ha = rec1[sA];
        uint4 hb = rec1[sB];
        uint4 hc = rec1[sC];
        uint4 hd = rec1[sD];
        float2 fa01 = unpack2h(ha.x), fa23 = unpack2h(ha.y), fa45 = unpack2h(ha.z), fa67 = unpack2h(ha.w);
        float2 fb01 = unpack2h(hb.x), fb23 = unpack2h(hb.y), fb45 = unpack2h(hb.z), fb67 = unpack2h(hb.w);
        float2 fc01 = unpack2h(hc.x), fc23 = unpack2h(hc.y), fc45 = unpack2h(hc.z), fc67 = unpack2h(hc.w);
        float2 fd01 = unpack2h(hd.x), fd23 = unpack2h(hd.y), fd45 = unpack2h(hd.z), fd67 = unpack2h(hd.w);
        float ssA = fa01.x*as0 + fa01.y*as1 + fa23.x*as2 + fa23.y*as3
                  + fa45.x*as4 + fa45.y*as5 + fa67.x*as6 + fa67.y*as7;
        float ssB = fb01.x*as0 + fb01.y*as1 + fb23.x*as2 + fb23.y*as3
                  + fb45.x*as4 + fb45.y*as5 + fb67.x*as6 + fb67.y*as7;
        float ssC = fc01.x*as0 + fc01.y*as1 + fc23.x*as2 + fc23.y*as3
                  + fc45.x*as4 + fc45.y*as5 + fc67.x*as6 + fc67.y*as7;
        float ssD = fd01.x*as0 + fd01.y*as1 + fd23.x*as2 + fd23.y*as3
                  + fd45.x*as4 + fd45.y*as5 + fd67.x*as6 + fd67.y*as7;
        float eA = ssA + sdvn; eA = (eA > 0.f) ? eA : NEG_SLOPE * eA;
        float eB = ssB + sdvn; eB = (eB > 0.f) ? eB : NEG_SLOPE * eB;
        float eC = ssC + sdvn; eC = (eC > 0.f) ? eC : NEG_SLOPE * eC;
        float eD = ssD + sdvn; eD = (eD > 0.f) ? eD : NEG_SLOPE * eD;
        float pA = __expf(eA - SHIFT1);
        float pB = __expf(eB - SHIFT1);
        float pC = __expf(eC - SHIFT1);
        float pD = __expf(eD - SHIFT1);
        z += (pA + pB) + (pC + pD);
        acc[0] += pA * fa01.x + pB * fb01.x + pC * fc01.x + pD * fd01.x;
        acc[1] += pA * fa01.y + pB * fb01.y + pC * fc01.y + pD * fd01.y;
        acc[2] += pA * fa23.x + pB * fb23.x + pC * fc23.x + pD * fd23.x;
        acc[3] += pA * fa23.y + pB * fb23.y + pC * fc23.y + pD * fd23.y;
        acc[4] += pA * fa45.x + pB * fb45.x + pC * fc45.x + pD * fd45.x;
        acc[5] += pA * fa45.y + pB * fb45.y + pC * fc45.y + pD * fd45.y;
        acc[6] += pA * fa67.x + pB * fb67.x + pC * fc67.x + pD * fd67.x;
        acc[7] += pA * fa67.y + pB * fb67.y + pC * fc67.y + pD * fd67.y;
    }
    for (; j < e1; j += 16) {
        int s = bdata[j];
        uint4 hv = rec1[s];
        float2 f01 = unpack2h(hv.x), f23 = unpack2h(hv.y);
        float2 f45 = unpack2h(hv.z), f67 = unpack2h(hv.w);
        float ss = f01.x*as0 + f01.y*as1 + f23.x*as2 + f23.y*as3
                 + f45.x*as4 + f45.y*as5 + f67.x*as6 + f67.y*as7;
        float e = ss + sdvn;
        e = (e > 0.f) ? e : NEG_SLOPE * e;
        float p = __expf(e - SHIFT1);
        z += p;
        acc[0] += p * f01.x; acc[1] += p * f01.y;
        acc[2] += p * f23.x; acc[3] += p * f23.y;
        acc[4] += p * f45.x; acc[5] += p * f45.y;
        acc[6] += p * f67.x; acc[7] += p * f67.y;
    }

#pragma unroll
    for (int off = 1; off < 16; off <<= 1) {
        z += __shfl_xor(z, off);
#pragma unroll
        for (int f = 0; f < HID; ++f) acc[f] += __shfl_xor(acc[f], off);
    }

    if (q == 0) {
        float inv = 1.f / (z + 1e-16f);
        float c0 = 0.f, c1 = 0.f;
#pragma unroll
        for (int f = 0; f < HID; ++f) {
            float hr = fmaxf(acc[f] * inv + b1[f], 0.f);
            c0 = fmaf(hr, W2[f * NCLS + 0], c0);
            c1 = fmaf(hr, W2[f * NCLS + 1], c1);
        }
        rec2[n] = make_float2(c0, c1);
    }
}

// ---------------- KAgg2: layer-2 agg, ONE float2 gather per edge -----------
__global__ __launch_bounds__(256) void kAgg2(
    const int* __restrict__ nptr, const unsigned int* __restrict__ bdata,
    const float2* __restrict__ rec2,
    const float* __restrict__ a2s, const float* __restrict__ a2d,
    const float* __restrict__ b2, float* __restrict__ out)
{
    int gi = blockIdx.x * 256 + threadIdx.x;
    int n = gi >> 4, q = gi & 15;
    if (n >= N_NODES) return;

    float ws0 = a2s[0], ws1 = a2s[1];
    float wd0 = a2d[0], wd1 = a2d[1];

    int e0 = nptr[n], e1 = nptr[n + 1];
    float2 rn = rec2[n];
    float sdvn = rn.x * wd0 + rn.y * wd1;
    float z = 0.f, a0 = 0.f, a1 = 0.f;

    int j = e0 + q;
    for (; j + 48 < e1; j += 64) {
        int sA = bdata[j];
        int sB = bdata[j + 16];
        int sC = bdata[j + 32];
        int sD = bdata[j + 48];
        float2 rA = rec2[sA];
        float2 rB = rec2[sB];
        float2 rC = rec2[sC];
        float2 rD = rec2[sD];
        float eA = rA.x * ws0 + rA.y * ws1 + sdvn; eA = (eA > 0.f) ? eA : NEG_SLOPE * eA;
        float eB = rB.x * ws0 + rB.y * ws1 + sdvn; eB = (eB > 0.f) ? eB : NEG_SLOPE * eB;
        float eC = rC.x * ws0 + rC.y * ws1 + sdvn; eC = (eC > 0.f) ? eC : NEG_SLOPE * eC;
        float eD = rD.x * ws0 + rD.y * ws1 + sdvn; eD = (eD > 0.f) ? eD : NEG_SLOPE * eD;
        float pA = __expf(eA - SHIFT2);
        float pB = __expf(eB - SHIFT2);
        float pC = __expf(eC - SHIFT2);
        float pD = __expf(eD - SHIFT2);
        z += (pA + pB) + (pC + pD);
        a0 += pA * rA.x + pB * rB.x + pC * rC.x + pD * rD.x;
        a1 += pA * rA.y + pB * rB.y + pC * rC.y + pD * rD.y;
    }
    for (; j < e1; j += 16) {
        int s = bdata[j];
        float2 r = rec2[s];
        float e = r.x * ws0 + r.y * ws1 + sdvn;
        e = (e > 0.f) ? e : NEG_SLOPE * e;
        float p = __expf(e - SHIFT2);
        z += p; a0 += p * r.x; a1 += p * r.y;
    }

#pragma unroll
    for (int off = 1; off < 16; off <<= 1) {
        z  += __shfl_xor(z, off);
        a0 += __shfl_xor(a0, off);
        a1 += __shfl_xor(a1, off);
    }

    if (q == 0) {
        float inv = 1.f / (z + 1e-16f);
        float o0 = a0 * inv + b2[0];
        float o1 = a1 * inv + b2[1];
        float mx = fmaxf(o0, o1);
        float lse = mx + __logf(__expf(o0 - mx) + __expf(o1 - mx));
        ((float2*)out)[n] = make_float2(o0 - lse, o1 - lse);
    }
}

// ---------------- host launch ----------------------------------------------
extern "C" void kernel_launch(void* const* d_in, const int* in_sizes, int n_in,
                              void* d_out, int out_size, void* d_ws, size_t ws_size,
                              hipStream_t stream) {
    const float* x   = (const float*)d_in[0];
    const float* W1  = (const float*)d_in[1];
    const float* a1s = (const float*)d_in[2];
    const float* a1d = (const float*)d_in[3];
    const float* b1  = (const float*)d_in[4];
    const float* W2  = (const float*)d_in[5];
    const float* a2s = (const float*)d_in[6];
    const float* a2d = (const float*)d_in[7];
    const float* b2  = (const float*)d_in[8];
    const int*   ei  = (const int*)d_in[9];
    const int* src = ei;
    const int* dst = ei + N_EDGES;

    char* ws = (char*)d_ws;
    uint4*  rec1  = (uint4*) (ws + 0);              // 1,600,000 (100000 x 16B)
    float*  s1d   = (float*) (ws + 1600000);        //   400,000
    float2* rec2  = (float2*)(ws + 2000000);        //   800,000
    int*    nptr  = (int*)   (ws + 2800000);        //   400,016
    int*    cbase = (int*)   (ws + 3200064);        //     1,568 -> pad
    int*    tot   = (int*)   (ws + 3201664);        //     1,564 -> pad
    unsigned int* bdata = (unsigned int*)(ws + 3203264);  // 25,600,000 -> ends 28,803,264
    int*    gcnt  = (int*)   (ws + 28803264);       // 782x391x4 = 1,223,048
    int*    lpre  = (int*)   (ws + 30026312);       // 391x782x4 = 1,223,048 -> ends 31,249,360

    float* out = (float*)d_out;

    k0_node<<<(N_NODES + 255) / 256, 256, 0, stream>>>(x, W1, a1d, rec1, s1d);
    kH_hist<<<NSTG, 256, 0, stream>>>(dst, gcnt);
    kS_scan<<<NBC, 256, 0, stream>>>(gcnt, lpre, tot);
    k2b_cscan<<<1, 512, 0, stream>>>(tot, cbase);
    kA_stage<<<NSTG, 1024, 0, stream>>>(src, dst, cbase, lpre, bdata);
    kB_sort<<<NBC, 1024, 0, stream>>>(cbase, bdata, nptr);
    kAgg1<<<(N_NODES * 16 + 255) / 256, 256, 0, stream>>>(nptr, bdata, rec1, s1d, a1s,
                                                          b1, W2, rec2);
    kAgg2<<<(N_NODES * 16 + 255) / 256, 256, 0, stream>>>(nptr, bdata, rec2,
                                                          a2s, a2d, b2, out);
}

// Round 22
// 130.520 us; speedup vs baseline: 1.0485x; 1.0137x over previous
//
#include <hip/hip_runtime.h>
#include <hip/hip_fp16.h>
#include <math.h>

#define N_NODES 100000
#define N_EDGES 6400000
#define F_IN 36
#define HID 8
#define NCLS 2
#define NEG_SLOPE 0.2f

#define COARSE 256                        // nodes per coarse bucket (dst >> 8)
#define NBC 391                           // ceil(N_NODES/256)
#define CAPC 18432                        // max edges per coarse bucket
#define CHUNK 8192                        // edges per scatter chunk
#define NSTG ((N_EDGES + CHUNK - 1) / CHUNK)   // 782
#define SHIFT1 8.0f                       // softmax shift (softmax is shift-invariant)
#define SHIFT2 16.0f

static __device__ __forceinline__ unsigned pack2h(float a, float b) {
    __half2 h = __float22half2_rn(make_float2(a, b));
    return *reinterpret_cast<unsigned*>(&h);
}
static __device__ __forceinline__ float2 unpack2h(unsigned u) {
    __half2 h = *reinterpret_cast<__half2*>(&u);
    return __half22float2(h);
}

// ------- K0: per-node rec1 (fp16 h) + s1d, FUSED per-chunk dst histogram ---
// grid = NSTG blocks; blocks <391 also do node work; all blocks do gcnt[g].
__global__ __launch_bounds__(256) void k0_node(
    const float* __restrict__ x, const float* __restrict__ W1,
    const float* __restrict__ a1d_g, const int* __restrict__ dst,
    uint4* __restrict__ rec1, float* __restrict__ s1d, int* __restrict__ gcnt)
{
    __shared__ float sW[F_IN * HID];
    __shared__ float sad[HID];
    __shared__ int lh[NBC];
    int tid = threadIdx.x, g = blockIdx.x;
    for (int i = tid; i < F_IN * HID; i += 256) sW[i] = W1[i];
    for (int i = tid; i < NBC; i += 256) lh[i] = 0;
    if (tid < HID) sad[tid] = a1d_g[tid];
    __syncthreads();

    int n = g * 256 + tid;
    if (n < N_NODES) {
        const float4* xp = (const float4*)(x + (size_t)n * F_IN);
        float h[HID];
#pragma unroll
        for (int f = 0; f < HID; ++f) h[f] = 0.f;
#pragma unroll
        for (int q = 0; q < F_IN / 4; ++q) {
            float4 v = xp[q];
            float vs[4] = {v.x, v.y, v.z, v.w};
#pragma unroll
            for (int j = 0; j < 4; ++j) {
                int k = q * 4 + j;
#pragma unroll
                for (int f = 0; f < HID; ++f) h[f] = fmaf(vs[j], sW[k * HID + f], h[f]);
            }
        }
        float sd = 0.f;
#pragma unroll
        for (int f = 0; f < HID; ++f) sd = fmaf(h[f], sad[f], sd);

        uint4 w;
        w.x = pack2h(h[0], h[1]);
        w.y = pack2h(h[2], h[3]);
        w.z = pack2h(h[4], h[5]);
        w.w = pack2h(h[6], h[7]);
        rec1[n] = w;
        s1d[n] = sd;
    }

    // per-chunk histogram (kH body)
    int e0 = g * CHUNK;
    int ne = N_EDGES - e0; if (ne > CHUNK) ne = CHUNK;
    int n4 = ne >> 2;
    const int4* dv = (const int4*)(dst + e0);
    for (int i = tid; i < n4; i += 256) {
        int4 d = dv[i];
        atomicAdd(&lh[d.x >> 8], 1);
        atomicAdd(&lh[d.y >> 8], 1);
        atomicAdd(&lh[d.z >> 8], 1);
        atomicAdd(&lh[d.w >> 8], 1);
    }
    __syncthreads();
    for (int i = tid; i < NBC; i += 256) gcnt[(size_t)g * NBC + i] = lh[i];
}

// ------- KS: per-bucket exclusive scan over chunks -> lpre[b][g], tot[b] ---
__global__ __launch_bounds__(256) void kS_scan(const int* __restrict__ gcnt,
                                               int* __restrict__ lpre, int* __restrict__ tot)
{
    __shared__ int sv[256];
    int b = blockIdx.x, tid = threadIdx.x;
    int carry = 0;
    const int ntile = (NSTG + 255) / 256;
    for (int t = 0; t < ntile; ++t) {
        int g = t * 256 + tid;
        int v = (g < NSTG) ? gcnt[(size_t)g * NBC + b] : 0;
        sv[tid] = v;
        __syncthreads();
        for (int off = 1; off < 256; off <<= 1) {
            int x = (tid >= off) ? sv[tid - off] : 0;
            __syncthreads();
            sv[tid] += x;
            __syncthreads();
        }
        if (g < NSTG) lpre[(size_t)b * NSTG + g] = carry + sv[tid] - v;
        carry += sv[255];
        __syncthreads();
    }
    if (tid == 0) tot[b] = carry;
}

// ------- K2b: scan bucket totals -> cbase ----------------------------------
__global__ __launch_bounds__(512) void k2b_cscan(const int* __restrict__ tot,
                                                 int* __restrict__ cbase)
{
    __shared__ int s[512];
    int tid = threadIdx.x;
    int v = (tid < NBC) ? tot[tid] : 0;
    s[tid] = v;
    __syncthreads();
    for (int off = 1; off < 512; off <<= 1) {
        int t = (tid >= off) ? s[tid - off] : 0;
        __syncthreads();
        s[tid] += t;
        __syncthreads();
    }
    int ex = s[tid] - v;
    if (tid < NBC) cbase[tid] = ex;
    if (tid == NBC) cbase[NBC] = ex;   // == N_EDGES
}

// ------- KA: staged scatter — NO global atomics ----------------------------
__global__ __launch_bounds__(1024) void kA_stage(
    const int* __restrict__ src, const int* __restrict__ dst,
    const int* __restrict__ cbase, const int* __restrict__ lpre,
    unsigned int* __restrict__ bdata)
{
    __shared__ unsigned int stg[CHUNK];          // 32 KB
    __shared__ unsigned short aux[CHUNK];        // 16 KB
    __shared__ int lh[NBC];
    __shared__ int lstart[NBC];
    __shared__ int lcur[NBC];
    __shared__ int tbase[NBC];
    int tid = threadIdx.x, g = blockIdx.x;

    for (int i = tid; i < NBC; i += 1024) lh[i] = 0;
    __syncthreads();

    int e0 = g * CHUNK;
    int ne = N_EDGES - e0; if (ne > CHUNK) ne = CHUNK;   // multiple of 4
    int n4 = ne >> 2;
    const int4* dv = (const int4*)(dst + e0);
    const int4* sv = (const int4*)(src + e0);

    int4 d0, s0, d1, s1;
    bool v0 = (tid < n4), v1 = (tid + 1024 < n4);
    if (v0) {
        d0 = dv[tid]; s0 = sv[tid];
        atomicAdd(&lh[d0.x >> 8], 1);
        atomicAdd(&lh[d0.y >> 8], 1);
        atomicAdd(&lh[d0.z >> 8], 1);
        atomicAdd(&lh[d0.w >> 8], 1);
    }
    if (v1) {
        d1 = dv[tid + 1024]; s1 = sv[tid + 1024];
        atomicAdd(&lh[d1.x >> 8], 1);
        atomicAdd(&lh[d1.y >> 8], 1);
        atomicAdd(&lh[d1.z >> 8], 1);
        atomicAdd(&lh[d1.w >> 8], 1);
    }
    __syncthreads();

    if (tid < 64) {
        int base = tid * 7;
        int cnt[7];
        int s = 0;
#pragma unroll
        for (int k = 0; k < 7; ++k) {
            int b = base + k;
            cnt[k] = (b < NBC) ? lh[b] : 0;
            s += cnt[k];
        }
        int inc = s;
#pragma unroll
        for (int off = 1; off < 64; off <<= 1) {
            int t2 = __shfl_up(inc, off);
            if (tid >= off) inc += t2;
        }
        int ex = inc - s;
#pragma unroll
        for (int k = 0; k < 7; ++k) {
            int b = base + k;
            if (b < NBC) { lstart[b] = ex; lcur[b] = ex; ex += cnt[k]; }
        }
    }
    __syncthreads();

    for (int b = tid; b < NBC; b += 1024) {
        tbase[b] = cbase[b] + lpre[(size_t)b * NSTG + g];
    }

    if (v0) {
        int b, p;
        b = d0.x >> 8; p = atomicAdd(&lcur[b], 1); stg[p] = (unsigned)s0.x | ((unsigned)(d0.x & 255) << 17); aux[p] = (unsigned short)b;
        b = d0.y >> 8; p = atomicAdd(&lcur[b], 1); stg[p] = (unsigned)s0.y | ((unsigned)(d0.y & 255) << 17); aux[p] = (unsigned short)b;
        b = d0.z >> 8; p = atomicAdd(&lcur[b], 1); stg[p] = (unsigned)s0.z | ((unsigned)(d0.z & 255) << 17); aux[p] = (unsigned short)b;
        b = d0.w >> 8; p = atomicAdd(&lcur[b], 1); stg[p] = (unsigned)s0.w | ((unsigned)(d0.w & 255) << 17); aux[p] = (unsigned short)b;
    }
    if (v1) {
        int b, p;
        b = d1.x >> 8; p = atomicAdd(&lcur[b], 1); stg[p] = (unsigned)s1.x | ((unsigned)(d1.x & 255) << 17); aux[p] = (unsigned short)b;
        b = d1.y >> 8; p = atomicAdd(&lcur[b], 1); stg[p] = (unsigned)s1.y | ((unsigned)(d1.y & 255) << 17); aux[p] = (unsigned short)b;
        b = d1.z >> 8; p = atomicAdd(&lcur[b], 1); stg[p] = (unsigned)s1.z | ((unsigned)(d1.z & 255) << 17); aux[p] = (unsigned short)b;
        b = d1.w >> 8; p = atomicAdd(&lcur[b], 1); stg[p] = (unsigned)s1.w | ((unsigned)(d1.w & 255) << 17); aux[p] = (unsigned short)b;
    }
    __syncthreads();

    for (int i = tid; i < ne; i += 1024) {
        int bb = aux[i];
        bdata[tbase[bb] + (i - lstart[bb])] = stg[i];
    }
}

// ------- KB: LDS->LDS node sort, coalesced writeback (1024T) ---------------
__global__ __launch_bounds__(1024) void kB_sort(
    const int* __restrict__ cbase, unsigned int* __restrict__ bdata,
    int* __restrict__ nptr)
{
    __shared__ unsigned int raw[CAPC];    // 72 KB
    __shared__ unsigned int srt[CAPC];    // 72 KB
    __shared__ int cnt[COARSE];
    __shared__ int sstart[COARSE];
    __shared__ int cur[COARSE];
    int tid = threadIdx.x;
    int c = blockIdx.x;
    int cb0 = cbase[c], cb1 = cbase[c + 1];
    int ne = cb1 - cb0;

    if (tid < COARSE) cnt[tid] = 0;
    __syncthreads();

    for (int i = tid; i < ne; i += 1024) {
        unsigned pk = bdata[cb0 + i];
        raw[i] = pk;
        atomicAdd(&cnt[pk >> 17], 1);
    }
    __syncthreads();

    if (tid < 64) {
        int base = tid * 4;
        int c0 = cnt[base], c1 = cnt[base + 1], c2 = cnt[base + 2], c3 = cnt[base + 3];
        int s = c0 + c1 + c2 + c3;
        int inc = s;
#pragma unroll
        for (int off = 1; off < 64; off <<= 1) {
            int t2 = __shfl_up(inc, off);
            if (tid >= off) inc += t2;
        }
        int ex = inc - s;
        sstart[base]     = ex; cur[base]     = ex; ex += c0;
        sstart[base + 1] = ex; cur[base + 1] = ex; ex += c1;
        sstart[base + 2] = ex; cur[base + 2] = ex; ex += c2;
        sstart[base + 3] = ex; cur[base + 3] = ex;
    }
    __syncthreads();

    if (tid < COARSE) {
        int nid = c * COARSE + tid;
        if (nid < N_NODES) nptr[nid] = cb0 + sstart[tid];
    }
    if (c == 0 && tid == 0) nptr[N_NODES] = N_EDGES;

    for (int i = tid; i < ne; i += 1024) {
        unsigned pk = raw[i];
        int p = atomicAdd(&cur[pk >> 17], 1);
        srt[p] = pk & 0x1FFFF;
    }
    __syncthreads();

    for (int i = tid; i < ne; i += 1024) bdata[cb0 + i] = srt[i];
}

// ---------------- KAgg1: layer-1 agg, ONE uint4 gather per edge ------------
__global__ __launch_bounds__(256) void kAgg1(
    const int* __restrict__ nptr, const unsigned int* __restrict__ bdata,
    const uint4* __restrict__ rec1, const float* __restrict__ s1d,
    const float* __restrict__ a1s_g,
    const float* __restrict__ b1, const float* __restrict__ W2,
    float2* __restrict__ rec2)
{
    int gi = blockIdx.x * 256 + threadIdx.x;
    int n = gi >> 4, q = gi & 15;
    if (n >= N_NODES) return;

    float as0 = a1s_g[0], as1 = a1s_g[1], as2 = a1s_g[2], as3 = a1s_g[3];
    float as4 = a1s_g[4], as5 = a1s_g[5], as6 = a1s_g[6], as7 = a1s_g[7];

    int e0 = nptr[n], e1 = nptr[n + 1];
    float sdvn = s1d[n];
    float z = 0.f;
    float acc[HID];
#pragma unroll
    for (int f = 0; f < HID; ++f) acc[f] = 0.f;

    int j = e0 + q;
    for (; j + 48 < e1; j += 64) {
        int sA = bdata[j], sB = bdata[j + 16], sC = bdata[j + 32], sD = bdata[j + 48];
        uint4 ha = rec1[sA];
        uint4 hb = rec1[sB];
        uint4 hc = rec1[sC];
        uint4 hd = rec1[sD];
        float2 fa01 = unpack2h(ha.x), fa23 = unpack2h(ha.y), fa45 = unpack2h(ha.z), fa67 = unpack2h(ha.w);
        float2 fb01 = unpack2h(hb.x), fb23 = unpack2h(hb.y), fb45 = unpack2h(hb.z), fb67 = unpack2h(hb.w);
        float2 fc01 = unpack2h(hc.x), fc23 = unpack2h(hc.y), fc45 = unpack2h(hc.z), fc67 = unpack2h(hc.w);
        float2 fd01 = unpack2h(hd.x), fd23 = unpack2h(hd.y), fd45 = unpack2h(hd.z), fd67 = unpack2h(hd.w);
        float ssA = fa01.x*as0 + fa01.y*as1 + fa23.x*as2 + fa23.y*as3
                  + fa45.x*as4 + fa45.y*as5 + fa67.x*as6 + fa67.y*as7;
        float ssB = fb01.x*as0 + fb01.y*as1 + fb23.x*as2 + fb23.y*as3
                  + fb45.x*as4 + fb45.y*as5 + fb67.x*as6 + fb67.y*as7;
        float ssC = fc01.x*as0 + fc01.y*as1 + fc23.x*as2 + fc23.y*as3
                  + fc45.x*as4 + fc45.y*as5 + fc67.x*as6 + fc67.y*as7;
        float ssD = fd01.x*as0 + fd01.y*as1 + fd23.x*as2 + fd23.y*as3
                  + fd45.x*as4 + fd45.y*as5 + fd67.x*as6 + fd67.y*as7;
        float eA = ssA + sdvn; eA = (eA > 0.f) ? eA : NEG_SLOPE * eA;
        float eB = ssB + sdvn; eB = (eB > 0.f) ? eB : NEG_SLOPE * eB;
        float eC = ssC + sdvn; eC = (eC > 0.f) ? eC : NEG_SLOPE * eC;
        float eD = ssD + sdvn; eD = (eD > 0.f) ? eD : NEG_SLOPE * eD;
        float pA = __expf(eA - SHIFT1);
        float pB = __expf(eB - SHIFT1);
        float pC = __expf(eC - SHIFT1);
        float pD = __expf(eD - SHIFT1);
        z += (pA + pB) + (pC + pD);
        acc[0] += pA * fa01.x + pB * fb01.x + pC * fc01.x + pD * fd01.x;
        acc[1] += pA * fa01.y + pB * fb01.y + pC * fc01.y + pD * fd01.y;
        acc[2] += pA * fa23.x + pB * fb23.x + pC * fc23.x + pD * fd23.x;
        acc[3] += pA * fa23.y + pB * fb23.y + pC * fc23.y + pD * fd23.y;
        acc[4] += pA * fa45.x + pB * fb45.x + pC * fc45.x + pD * fd45.x;
        acc[5] += pA * fa45.y + pB * fb45.y + pC * fc45.y + pD * fd45.y;
        acc[6] += pA * fa67.x + pB * fb67.x + pC * fc67.x + pD * fd67.x;
        acc[7] += pA * fa67.y + pB * fb67.y + pC * fc67.y + pD * fd67.y;
    }
    for (; j < e1; j += 16) {
        int s = bdata[j];
        uint4 hv = rec1[s];
        float2 f01 = unpack2h(hv.x), f23 = unpack2h(hv.y);
        float2 f45 = unpack2h(hv.z), f67 = unpack2h(hv.w);
        float ss = f01.x*as0 + f01.y*as1 + f23.x*as2 + f23.y*as3
                 + f45.x*as4 + f45.y*as5 + f67.x*as6 + f67.y*as7;
        float e = ss + sdvn;
        e = (e > 0.f) ? e : NEG_SLOPE * e;
        float p = __expf(e - SHIFT1);
        z += p;
        acc[0] += p * f01.x; acc[1] += p * f01.y;
        acc[2] += p * f23.x; acc[3] += p * f23.y;
        acc[4] += p * f45.x; acc[5] += p * f45.y;
        acc[6] += p * f67.x; acc[7] += p * f67.y;
    }

#pragma unroll
    for (int off = 1; off < 16; off <<= 1) {
        z += __shfl_xor(z, off);
#pragma unroll
        for (int f = 0; f < HID; ++f) acc[f] += __shfl_xor(acc[f], off);
    }

    if (q == 0) {
        float inv = 1.f / (z + 1e-16f);
        float c0 = 0.f, c1 = 0.f;
#pragma unroll
        for (int f = 0; f < HID; ++f) {
            float hr = fmaxf(acc[f] * inv + b1[f], 0.f);
            c0 = fmaf(hr, W2[f * NCLS + 0], c0);
            c1 = fmaf(hr, W2[f * NCLS + 1], c1);
        }
        rec2[n] = make_float2(c0, c1);
    }
}

// ---------------- KAgg2: layer-2 agg, ONE float2 gather per edge -----------
__global__ __launch_bounds__(256) void kAgg2(
    const int* __restrict__ nptr, const unsigned int* __restrict__ bdata,
    const float2* __restrict__ rec2,
    const float* __restrict__ a2s, const float* __restrict__ a2d,
    const float* __restrict__ b2, float* __restrict__ out)
{
    int gi = blockIdx.x * 256 + threadIdx.x;
    int n = gi >> 4, q = gi & 15;
    if (n >= N_NODES) return;

    float ws0 = a2s[0], ws1 = a2s[1];
    float wd0 = a2d[0], wd1 = a2d[1];

    int e0 = nptr[n], e1 = nptr[n + 1];
    float2 rn = rec2[n];
    float sdvn = rn.x * wd0 + rn.y * wd1;
    float z = 0.f, a0 = 0.f, a1 = 0.f;

    int j = e0 + q;
    for (; j + 48 < e1; j += 64) {
        int sA = bdata[j];
        int sB = bdata[j + 16];
        int sC = bdata[j + 32];
        int sD = bdata[j + 48];
        float2 rA = rec2[sA];
        float2 rB = rec2[sB];
        float2 rC = rec2[sC];
        float2 rD = rec2[sD];
        float eA = rA.x * ws0 + rA.y * ws1 + sdvn; eA = (eA > 0.f) ? eA : NEG_SLOPE * eA;
        float eB = rB.x * ws0 + rB.y * ws1 + sdvn; eB = (eB > 0.f) ? eB : NEG_SLOPE * eB;
        float eC = rC.x * ws0 + rC.y * ws1 + sdvn; eC = (eC > 0.f) ? eC : NEG_SLOPE * eC;
        float eD = rD.x * ws0 + rD.y * ws1 + sdvn; eD = (eD > 0.f) ? eD : NEG_SLOPE * eD;
        float pA = __expf(eA - SHIFT2);
        float pB = __expf(eB - SHIFT2);
        float pC = __expf(eC - SHIFT2);
        float pD = __expf(eD - SHIFT2);
        z += (pA + pB) + (pC + pD);
        a0 += pA * rA.x + pB * rB.x + pC * rC.x + pD * rD.x;
        a1 += pA * rA.y + pB * rB.y + pC * rC.y + pD * rD.y;
    }
    for (; j < e1; j += 16) {
        int s = bdata[j];
        float2 r = rec2[s];
        float e = r.x * ws0 + r.y * ws1 + sdvn;
        e = (e > 0.f) ? e : NEG_SLOPE * e;
        float p = __expf(e - SHIFT2);
        z += p; a0 += p * r.x; a1 += p * r.y;
    }

#pragma unroll
    for (int off = 1; off < 16; off <<= 1) {
        z  += __shfl_xor(z, off);
        a0 += __shfl_xor(a0, off);
        a1 += __shfl_xor(a1, off);
    }

    if (q == 0) {
        float inv = 1.f / (z + 1e-16f);
        float o0 = a0 * inv + b2[0];
        float o1 = a1 * inv + b2[1];
        float mx = fmaxf(o0, o1);
        float lse = mx + __logf(__expf(o0 - mx) + __expf(o1 - mx));
        ((float2*)out)[n] = make_float2(o0 - lse, o1 - lse);
    }
}

// ---------------- host launch ----------------------------------------------
extern "C" void kernel_launch(void* const* d_in, const int* in_sizes, int n_in,
                              void* d_out, int out_size, void* d_ws, size_t ws_size,
                              hipStream_t stream) {
    const float* x   = (const float*)d_in[0];
    const float* W1  = (const float*)d_in[1];
    const float* a1s = (const float*)d_in[2];
    const float* a1d = (const float*)d_in[3];
    const float* b1  = (const float*)d_in[4];
    const float* W2  = (const float*)d_in[5];
    const float* a2s = (const float*)d_in[6];
    const float* a2d = (const float*)d_in[7];
    const float* b2  = (const float*)d_in[8];
    const int*   ei  = (const int*)d_in[9];
    const int* src = ei;
    const int* dst = ei + N_EDGES;

    char* ws = (char*)d_ws;
    uint4*  rec1  = (uint4*) (ws + 0);              // 1,600,000 (100000 x 16B)
    float*  s1d   = (float*) (ws + 1600000);        //   400,000
    float2* rec2  = (float2*)(ws + 2000000);        //   800,000
    int*    nptr  = (int*)   (ws + 2800000);        //   400,016
    int*    cbase = (int*)   (ws + 3200064);        //     1,568 -> pad
    int*    tot   = (int*)   (ws + 3201664);        //     1,564 -> pad
    unsigned int* bdata = (unsigned int*)(ws + 3203264);  // 25,600,000 -> ends 28,803,264
    int*    gcnt  = (int*)   (ws + 28803264);       // 782x391x4 = 1,223,048
    int*    lpre  = (int*)   (ws + 30026312);       // 391x782x4 = 1,223,048 -> ends 31,249,360

    float* out = (float*)d_out;

    k0_node<<<NSTG, 256, 0, stream>>>(x, W1, a1d, dst, rec1, s1d, gcnt);
    kS_scan<<<NBC, 256, 0, stream>>>(gcnt, lpre, tot);
    k2b_cscan<<<1, 512, 0, stream>>>(tot, cbase);
    kA_stage<<<NSTG, 1024, 0, stream>>>(src, dst, cbase, lpre, bdata);
    kB_sort<<<NBC, 1024, 0, stream>>>(cbase, bdata, nptr);
    kAgg1<<<(N_NODES * 16 + 255) / 256, 256, 0, stream>>>(nptr, bdata, rec1, s1d, a1s,
                                                          b1, W2, rec2);
    kAgg2<<<(N_NODES * 16 + 255) / 256, 256, 0, stream>>>(nptr, bdata, rec2,
                                                          a2s, a2d, b2, out);
}